// Round 4
// baseline (332.337 us; speedup 1.0000x reference)
//
#include <hip/hip_runtime.h>
#include <hip/hip_cooperative_groups.h>
#include <math.h>

namespace cg = cooperative_groups;

#define PI_D 3.14159265358979323846
#define PI_F 3.14159265358979323846f

typedef _Float16 half8 __attribute__((ext_vector_type(8)));
typedef _Float16 half2v __attribute__((ext_vector_type(2)));
typedef float floatx4 __attribute__((ext_vector_type(4)));
#define MFMA16(a,b,c) __builtin_amdgcn_mfma_f32_16x16x32_f16(a,b,c,0,0,0)

struct KParams {
  const float *inp, *scale, *sigma, *A, *icmp;
  const float *W1, *b1, *W2, *b2, *Wg, *Wc31, *bc31, *Wc32, *bc32;
  float *ft, *h1, *h2, *ftmax, *bmax, *wq;
  _Float16 *VswH, *VswL, *W2swH, *W2swL;
  float *out, *ftg;
};

// Single cooperative kernel: 256 blocks x 512 threads, 1 block/CU (LDS-limited).
// stages: prep -> scatter -> conv1 -> conv2 -> reduce -> head -> final
__global__ __launch_bounds__(512, 2) void k_main(KParams p) {
  __shared__ __align__(16) char smem[157440];
  cg::grid_group grid = cg::this_grid();
  const int blk = blockIdx.x;          // 0..255
  const int t = threadIdx.x;           // 0..511

  // ================= stage 0: prep (zero ft, wq, prepV, prepW2) =================
  {
    int flat = blk * 512 + t;          // 0..131071
    // prepV: V[(g,d),c] = Wg[c,g]*Wc31[d,c], split f16, A-frag swizzled
    {
      int jj = flat & 7;
      int l  = (flat >> 3) & 63;
      int rest = flat >> 9;            // mt*2 + ks
      int ks = rest & 1, mt = rest >> 1;
      int c = ks*32 + (l >> 4)*8 + jj;
      int m = mt*16 + (l & 15);
      int g = m >> 6, d = m & 63;
      float val = p.Wg[c*32 + g] * p.Wc31[d*128 + c];
      _Float16 hi = (_Float16)val;
      p.VswH[flat] = hi;
      p.VswL[flat] = (_Float16)(val - (float)hi);
    }
    if (flat < 2048) {                 // prepW2
      int jj = flat & 7;
      int l  = (flat >> 3) & 63;
      int rest = flat >> 9;
      int ks = rest & 1, mt2 = rest >> 1;
      int e = mt2*16 + (l & 15);
      int d = ks*32 + (l >> 4)*8 + jj;
      float val = p.Wc32[e*64 + d];
      _Float16 hi = (_Float16)val;
      p.W2swH[flat] = hi;
      p.W2swL[flat] = (_Float16)(val - (float)hi);
    }
    if (flat < 16384) ((float4*)p.ft)[flat] = make_float4(0.f, 0.f, 0.f, 0.f);
    if (blk == 255 && t < 32) {        // quadrature weights (fp64, bw=16)
      double jj = 2.0*(double)t + 1.0;
      double theta = PI_D * jj / 64.0;
      double s = 0.0;
      for (int k = 0; k < 16; ++k)
        s += sin(jj * (double)(2*k+1) * PI_D / 64.0) / (double)(2*k+1);
      p.wq[t] = (float)((2.0/16.0) * sin(theta) * s);
    }
  }
  grid.sync();

  // ================= stage 1: scatter =================
  {
    float scale = p.scale[0], sigma = p.sigma[0], A = p.A[0], icomp = p.icmp[0];
#pragma unroll
    for (int ii = 0; ii < 2; ++ii) {
      int i = blk * 512 + t + ii * 131072;   // 0..262143
      int b = i >> 15;
      float x = p.inp[i*3+0];
      float y = p.inp[i*3+1];
      float z = p.inp[i*3+2];
      float r = sqrtf(x*x + y*y + z*z);
      r = fmaxf(r, 0.1f);
      float ctv = fminf(fmaxf(z / r, -1.0f), 1.0f);
      float theta = acosf(ctv);
      float phi = atan2f(y, x) + PI_F;
      float ct = theta * (32.0f / PI_F);
      float cp = phi * (32.0f / (2.0f * PI_F));
      float cr = r / scale * 8.0f;
      int it = (int)floorf(ct); it = min(max(it, 0), 31);
      int ip = (int)floorf(cp); ip = min(max(ip, 0), 31);
      int ir = (int)floorf(cr); ir = min(max(ir, 0), 7);
      float dt = ct - ((float)it + icomp);
      float dp = cp - ((float)ip + icomp);
      float dr = cr - ((float)ir + icomp);
      float d2 = dt*dt + dp*dp + dr*dr;
      float w = A * expf(-d2 / (2.0f * sigma * sigma));
      atomicAdd(&p.ft[((b*8 + ir)*32 + it)*32 + ip], w);
    }
  }
  grid.sync();

  // ================= stage 2: conv1 (8,8,32,32)->(8,32,32,32) =================
  {
    int b = blk >> 5, oc = blk & 31;
    float* Ws = (float*)smem;          // 72 floats
    if (t < 72) Ws[t] = p.W1[oc*72 + t];
    __syncthreads();
    const float* fb = p.ft + b*8192;
    float bias = p.b1[oc];
#pragma unroll
    for (int pp = 0; pp < 2; ++pp) {
      int px = t + pp*512;
      int x = px >> 5, y = px & 31;
      float acc = bias;
      for (int ic = 0; ic < 8; ++ic) {
        const float* fc = fb + ic*1024;
        const float* wr = Ws + ic*9;
#pragma unroll
        for (int dx = -1; dx <= 1; ++dx) {
          int xx = x + dx;
          bool okx = ((unsigned)xx < 32u);
#pragma unroll
          for (int dy = -1; dy <= 1; ++dy) {
            int yy = y + dy;
            float v = (okx && ((unsigned)yy < 32u)) ? fc[xx*32 + yy] : 0.f;
            acc = fmaf(v, wr[(dx+1)*3 + (dy+1)], acc);
          }
        }
      }
      p.h1[(b*32 + oc)*1024 + px] = fmaxf(acc, 0.f);
    }
  }
  grid.sync();

  // ================= stage 3: conv2 (8,32,32,32)->(8,64,32,32) =================
  {
    int b = blk >> 5, q = blk & 31;
    int oc0 = (q >> 1) * 4, xh = q & 1;
    float* Ws = (float*)smem;          // 1152 floats
    for (int idx = t; idx < 4*288; idx += 512) Ws[idx] = p.W2[oc0*288 + idx];
    __syncthreads();
    int x = xh*16 + (t >> 5), y = t & 31;
    float a0 = p.b2[oc0+0], a1 = p.b2[oc0+1], a2 = p.b2[oc0+2], a3 = p.b2[oc0+3];
    const float* hb = p.h1 + b*32*1024;
    for (int ic = 0; ic < 32; ++ic) {
      const float* hc = hb + ic*1024;
      const float* w0 = Ws + 0*288 + ic*9;
      const float* w1 = Ws + 1*288 + ic*9;
      const float* w2 = Ws + 2*288 + ic*9;
      const float* w3 = Ws + 3*288 + ic*9;
#pragma unroll
      for (int dx = -1; dx <= 1; ++dx) {
        int xx = x + dx;
        bool okx = ((unsigned)xx < 32u);
#pragma unroll
        for (int dy = -1; dy <= 1; ++dy) {
          int yy = y + dy;
          float v = (okx && ((unsigned)yy < 32u)) ? hc[xx*32 + yy] : 0.f;
          int k = (dx+1)*3 + (dy+1);
          a0 = fmaf(v, w0[k], a0);
          a1 = fmaf(v, w1[k], a1);
          a2 = fmaf(v, w2[k], a2);
          a3 = fmaf(v, w3[k], a3);
        }
      }
    }
    int pp = x*32 + y;
    p.h2[(b*64 + oc0+0)*1024 + pp] = fmaxf(a0, 0.f);
    p.h2[(b*64 + oc0+1)*1024 + pp] = fmaxf(a1, 0.f);
    p.h2[(b*64 + oc0+2)*1024 + pp] = fmaxf(a2, 0.f);
    p.h2[(b*64 + oc0+3)*1024 + pp] = fmaxf(a3, 0.f);
  }
  grid.sync();

  // ================= stage 4: reduce -> ftmax (2 (b,c) pairs per block) =================
  {
    float* wqs = (float*)smem;         // 32
    float* red = (float*)smem + 32;    // 512
    int half = t >> 8;                 // 0/1
    int tt = t & 255;
    int pair = blk*2 + half;           // 0..511
    int b = pair >> 6, c = pair & 63;
    if (t < 32) wqs[t] = p.wq[t];
    __syncthreads();
    const float* hb = p.h2 + (b*64 + c)*1024;
    float acc = 0.f;
    for (int i = tt; i < 1024; i += 256) acc = fmaf(hb[i], wqs[i & 31], acc);
    red[half*256 + tt] = acc;
    __syncthreads();
    for (int s2 = 128; s2 > 0; s2 >>= 1) {
      if (tt < s2) red[half*256 + tt] += red[half*256 + tt + s2];
      __syncthreads();
    }
    if (tt == 0) {
      float sg = 0.f;
      for (int g = 0; g < 32; ++g) sg += p.Wg[c*32 + g];
      p.ftmax[b*64 + c] = sg * red[half*256];
    }
  }
  grid.sync();

  // ================= stage 5: head (MFMA split-f16) =================
  {
    _Float16* h3H = (_Float16*)smem;                 // 512*72
    _Float16* h3L = (_Float16*)(smem + 73728);       // 512*72
    _Float16* h2H = (_Float16*)(smem + 147456);      // 32*72
    _Float16* h2L = (_Float16*)(smem + 152064);      // 32*72
    float* Ks     = (float*)(smem + 156672);         // 64
    float* vbuf2  = (float*)(smem + 156928);         // 128
    const half8* VswH  = (const half8*)p.VswH;
    const half8* VswL  = (const half8*)p.VswL;
    const half8* W2swH = (const half8*)p.W2swH;
    const half8* W2swL = (const half8*)p.W2swL;

    int b = blk >> 5, x = blk & 31;
    int lane = t & 63, w = t >> 6;
    int n16 = lane & 15, quad = lane >> 4;

    for (int idx = t; idx < 2048; idx += 512) {
      int c = idx & 63, y = idx >> 6;
      float v = p.h2[(b*64 + c)*1024 + x*32 + y];
      _Float16 hi = (_Float16)v;
      h2H[y*72 + c] = hi;
      h2L[y*72 + c] = (_Float16)(v - (float)hi);
    }
    if (t < 64) {
      float acc = p.bc31[t];
      for (int c = 0; c < 64; ++c)
        acc = fmaf(p.Wc31[t*128 + 64 + c], p.ftmax[b*64 + c], acc);
      Ks[t] = acc;
    }
    __syncthreads();

    half8 bh00, bh01, bh10, bh11, bl00, bl01, bl10, bl11;
    {
      int a00 = (0*16 + n16)*72 + 0*32 + quad*8;
      int a01 = (0*16 + n16)*72 + 1*32 + quad*8;
      int a10 = (1*16 + n16)*72 + 0*32 + quad*8;
      int a11 = (1*16 + n16)*72 + 1*32 + quad*8;
      bh00 = *(const half8*)&h2H[a00];  bl00 = *(const half8*)&h2L[a00];
      bh01 = *(const half8*)&h2H[a01];  bl01 = *(const half8*)&h2L[a01];
      bh10 = *(const half8*)&h2H[a10];  bl10 = *(const half8*)&h2L[a10];
      bh11 = *(const half8*)&h2H[a11];  bl11 = *(const half8*)&h2L[a11];
    }
    int mt2 = w & 1;
    half8 a2h0 = W2swH[(mt2*2 + 0)*64 + lane];
    half8 a2h1 = W2swH[(mt2*2 + 1)*64 + lane];
    half8 a2l0 = W2swL[(mt2*2 + 0)*64 + lane];
    half8 a2l1 = W2swL[(mt2*2 + 1)*64 + lane];
    float bias_e[4];
#pragma unroll
    for (int r = 0; r < 4; ++r) bias_e[r] = p.bc32[mt2*16 + quad*4 + r];

    float vmax[4] = {-3.4e38f, -3.4e38f, -3.4e38f, -3.4e38f};

    for (int h = 0; h < 2; ++h) {
      if (h) __syncthreads();
      for (int i = 0; i < 8; ++i) {
        int mt = h*64 + w*8 + i;
        half8 ah0 = VswH[(mt*2 + 0)*64 + lane];
        half8 ah1 = VswH[(mt*2 + 1)*64 + lane];
        half8 al0 = VswL[(mt*2 + 0)*64 + lane];
        half8 al1 = VswL[(mt*2 + 1)*64 + lane];
        floatx4 acc0 = {0.f, 0.f, 0.f, 0.f};
        floatx4 acc1 = {0.f, 0.f, 0.f, 0.f};
        acc0 = MFMA16(ah0, bh00, acc0);  acc1 = MFMA16(ah0, bh10, acc1);
        acc0 = MFMA16(ah0, bl00, acc0);  acc1 = MFMA16(ah0, bl10, acc1);
        acc0 = MFMA16(al0, bh00, acc0);  acc1 = MFMA16(al0, bh10, acc1);
        acc0 = MFMA16(ah1, bh01, acc0);  acc1 = MFMA16(ah1, bh11, acc1);
        acc0 = MFMA16(ah1, bl01, acc0);  acc1 = MFMA16(ah1, bl11, acc1);
        acc0 = MFMA16(al1, bh01, acc0);  acc1 = MFMA16(al1, bh11, acc1);
        int g = mt >> 2, gl = g & 15;
        int dbase = (mt & 3)*16 + quad*4;
        float4 kv = *(const float4*)&Ks[dbase];
#pragma unroll
        for (int nt = 0; nt < 2; ++nt) {
          floatx4 a = nt ? acc1 : acc0;
          int y = nt*16 + n16;
          int rowc = y*16 + gl;
          int dsw = (dbase + y*8) & 63;
          float v0 = fmaxf(a[0] + kv.x, 0.f);
          float v1 = fmaxf(a[1] + kv.y, 0.f);
          float v2 = fmaxf(a[2] + kv.z, 0.f);
          float v3 = fmaxf(a[3] + kv.w, 0.f);
          _Float16 c0 = (_Float16)v0, c1 = (_Float16)v1, c2 = (_Float16)v2, c3 = (_Float16)v3;
          half2v hh0 = {c0, c1}, hh1 = {c2, c3};
          half2v ll0 = {(_Float16)(v0 - (float)c0), (_Float16)(v1 - (float)c1)};
          half2v ll1 = {(_Float16)(v2 - (float)c2), (_Float16)(v3 - (float)c3)};
          int base = rowc*72 + dsw;
          *(half2v*)&h3H[base]     = hh0;
          *(half2v*)&h3H[base + 2] = hh1;
          *(half2v*)&h3L[base]     = ll0;
          *(half2v*)&h3L[base + 2] = ll1;
        }
      }
      __syncthreads();
      for (int i = 0; i < 8; ++i) {
        int nt2 = (w >> 1)*8 + i;
        int rowc = nt2*16 + n16;
        floatx4 acc = {0.f, 0.f, 0.f, 0.f};
        {
          int dsw0 = (0*32 + quad*8 + nt2*8) & 63;
          int dsw1 = (1*32 + quad*8 + nt2*8) & 63;
          half8 b2h0 = *(const half8*)&h3H[rowc*72 + dsw0];
          half8 b2l0 = *(const half8*)&h3L[rowc*72 + dsw0];
          half8 b2h1 = *(const half8*)&h3H[rowc*72 + dsw1];
          half8 b2l1 = *(const half8*)&h3L[rowc*72 + dsw1];
          acc = MFMA16(a2h0, b2h0, acc);
          acc = MFMA16(a2h0, b2l0, acc);
          acc = MFMA16(a2l0, b2h0, acc);
          acc = MFMA16(a2h1, b2h1, acc);
          acc = MFMA16(a2h1, b2l1, acc);
          acc = MFMA16(a2l1, b2h1, acc);
        }
        int y = nt2, g = h*16 + n16;
        size_t base = (((size_t)(b*32 + mt2*16 + quad*4))*1024 + (size_t)(x*32 + y))*32 + g;
#pragma unroll
        for (int r = 0; r < 4; ++r) {
          float v = acc[r] + bias_e[r];
          p.out[base + (size_t)r*32768] = v;
          vmax[r] = fmaxf(vmax[r], v);
        }
      }
    }
#pragma unroll
    for (int m = 1; m < 16; m <<= 1) {
#pragma unroll
      for (int r = 0; r < 4; ++r)
        vmax[r] = fmaxf(vmax[r], __shfl_xor(vmax[r], m, 64));
    }
    if (n16 == 0) {
#pragma unroll
      for (int r = 0; r < 4; ++r) vbuf2[w*16 + quad*4 + r] = vmax[r];
    }
    __syncthreads();
    if (t < 32) {
      int e = t, m2 = e >> 4, el = e & 15;
      float mm = fmaxf(fmaxf(vbuf2[(m2+0)*16 + el], vbuf2[(m2+2)*16 + el]),
                       fmaxf(vbuf2[(m2+4)*16 + el], vbuf2[(m2+6)*16 + el]));
      p.bmax[blk*32 + e] = mm;
    }
  }
  grid.sync();

  // ================= stage 6: final ft_g =================
  if (blk == 0 && t < 256) {
    int b = t >> 5, e = t & 31;
    float m = -3.4e38f;
    for (int x = 0; x < 32; ++x) m = fmaxf(m, p.bmax[(b*32 + x)*32 + e]);
    p.ftg[b*32 + e] = m;
  }
}

extern "C" void kernel_launch(void* const* d_in, const int* in_sizes, int n_in,
                              void* d_out, int out_size, void* d_ws, size_t ws_size,
                              hipStream_t stream) {
  float* ws = (float*)d_ws;
  KParams prm;
  prm.inp   = (const float*)d_in[0];
  prm.scale = (const float*)d_in[1];
  prm.sigma = (const float*)d_in[2];
  prm.A     = (const float*)d_in[3];
  prm.icmp  = (const float*)d_in[4];
  // d_in[5]=res_pt(32), d_in[6]=res_r(8) — compile-time constants here
  prm.W1   = (const float*)d_in[7];
  prm.b1   = (const float*)d_in[8];
  prm.W2   = (const float*)d_in[9];
  prm.b2   = (const float*)d_in[10];
  prm.Wg   = (const float*)d_in[11];
  prm.Wc31 = (const float*)d_in[12];
  prm.bc31 = (const float*)d_in[13];
  prm.Wc32 = (const float*)d_in[14];
  prm.bc32 = (const float*)d_in[15];

  prm.ft    = ws;               // 65536
  prm.h1    = ws + 65536;       // 262144
  prm.h2    = ws + 327680;      // 524288
  prm.ftmax = ws + 851968;      // 512
  prm.bmax  = ws + 852480;      // 8192
  prm.wq    = ws + 860672;      // 32
  prm.VswH  = (_Float16*)(ws + 860704);   // 131072 f16
  prm.VswL  = (_Float16*)(ws + 926240);   // 131072 f16
  prm.W2swH = (_Float16*)(ws + 991776);   // 2048 f16
  prm.W2swL = (_Float16*)(ws + 992800);   // 2048 f16
  prm.out   = (float*)d_out;    // 8388608
  prm.ftg   = prm.out + 8388608;

  void* kargs[] = { (void*)&prm };
  hipLaunchCooperativeKernel((void*)k_main, dim3(256), dim3(512), kargs, 0, stream);
}

// Round 5
// 186.052 us; speedup vs baseline: 1.7863x; 1.7863x over previous
//
#include <hip/hip_runtime.h>
#include <math.h>

#define PI_D 3.14159265358979323846
#define PI_F 3.14159265358979323846f

typedef _Float16 half8 __attribute__((ext_vector_type(8)));
typedef _Float16 half4v __attribute__((ext_vector_type(4)));
typedef float floatx4 __attribute__((ext_vector_type(4)));
#define MFMA16(a,b,c) __builtin_amdgcn_mfma_f32_16x16x32_f16(a,b,c,0,0,0)

// ---------------- prep: zero ft/WS, wq, sgs, V-frags, W2-frags (one dispatch) ----------
__global__ void k_prep(const float* __restrict__ Wg, const float* __restrict__ Wc31,
                       const float* __restrict__ Wc32,
                       _Float16* __restrict__ VswH, _Float16* __restrict__ VswL,
                       _Float16* __restrict__ W2swH, _Float16* __restrict__ W2swL,
                       float* __restrict__ ft, float* __restrict__ WS,
                       float* __restrict__ wq, float* __restrict__ sgs) {
  int flat = blockIdx.x * 256 + threadIdx.x;        // 0 .. 131071
  // prepV: V[(g,d),c] = Wg[c,g]*Wc31[d,c], split f16, A-frag swizzled
  {
    int jj = flat & 7;
    int l  = (flat >> 3) & 63;
    int rest = flat >> 9;                           // mt*2 + ks
    int ks = rest & 1, mt = rest >> 1;              // mt 0..127
    int c = ks*32 + (l >> 4)*8 + jj;
    int m = mt*16 + (l & 15);                       // m = g*64 + d
    int g = m >> 6, d = m & 63;
    float val = Wg[c*32 + g] * Wc31[d*128 + c];
    _Float16 hi = (_Float16)val;
    VswH[flat] = hi;
    VswL[flat] = (_Float16)(val - (float)hi);
  }
  if (flat < 2048) {                                // prepW2 (M-side = e)
    int jj = flat & 7;
    int l  = (flat >> 3) & 63;
    int rest = flat >> 9;
    int ks = rest & 1, mt2 = rest >> 1;
    int e = mt2*16 + (l & 15);
    int d = ks*32 + (l >> 4)*8 + jj;
    float val = Wc32[e*64 + d];
    _Float16 hi = (_Float16)val;
    W2swH[flat] = hi;
    W2swL[flat] = (_Float16)(val - (float)hi);
  }
  if (flat < 16384) ((float4*)ft)[flat] = make_float4(0.f, 0.f, 0.f, 0.f);
  if (flat < 32) {                                  // quadrature weights (fp64, bw=16)
    double jj = 2.0*(double)flat + 1.0;
    double theta = PI_D * jj / 64.0;
    double s = 0.0;
    for (int k = 0; k < 16; ++k)
      s += sin(jj * (double)(2*k+1) * PI_D / 64.0) / (double)(2*k+1);
    wq[flat] = (float)((2.0/16.0) * sin(theta) * s);
  } else if (flat < 96) {                           // sgs[c] = sum_g Wg[c,g]
    int c = flat - 32;
    float s = 0.f;
    for (int g = 0; g < 32; ++g) s += Wg[c*32 + g];
    sgs[c] = s;
  } else if (flat < 608) {
    WS[flat - 96] = 0.f;                            // zero ftmax accumulator
  }
}

// ---------------- scatter: remap + gaussian gridding (w channel only, fp32) ----------------
__global__ void k_scatter(const float* __restrict__ inp,
                          const float* __restrict__ p_scale,
                          const float* __restrict__ p_sigma,
                          const float* __restrict__ p_A,
                          const float* __restrict__ p_ic,
                          float* __restrict__ ft) {
  int i = blockIdx.x * 256 + threadIdx.x;           // 0 .. 262143
  float scale = p_scale[0];
  float sigma = p_sigma[0];
  float A     = p_A[0];
  float icomp = p_ic[0];
  int b = i >> 15;
  float x = inp[i*3+0];
  float y = inp[i*3+1];
  float z = inp[i*3+2];
  float r = sqrtf(x*x + y*y + z*z);
  r = fmaxf(r, 0.1f);
  float ctv = fminf(fmaxf(z / r, -1.0f), 1.0f);
  float theta = acosf(ctv);
  float phi = atan2f(y, x) + PI_F;
  float ct = theta * (32.0f / PI_F);
  float cp = phi * (32.0f / (2.0f * PI_F));
  float cr = r / scale * 8.0f;
  int it = (int)floorf(ct); it = min(max(it, 0), 31);
  int ip = (int)floorf(cp); ip = min(max(ip, 0), 31);
  int ir = (int)floorf(cr); ir = min(max(ir, 0), 7);
  float dt = ct - ((float)it + icomp);
  float dp = cp - ((float)ip + icomp);
  float dr = cr - ((float)ir + icomp);
  float d2 = dt*dt + dp*dp + dr*dr;
  float w = A * expf(-d2 / (2.0f * sigma * sigma));
  atomicAdd(&ft[((b*8 + ir)*32 + it)*32 + ip], w);
}

// ---------------- conv1: (8,8,32,32) -> (8,32,32,32), 3x3 SAME + relu ----------------
__global__ void k_conv1(const float* __restrict__ ft, const float* __restrict__ W,
                        const float* __restrict__ bias, float* __restrict__ h1) {
  int blk = blockIdx.x;            // 256 = b(8) * oc(32)
  int b = blk >> 5, oc = blk & 31;
  __shared__ float Ws[72];
  int t = threadIdx.x;             // 1024
  if (t < 72) Ws[t] = W[oc*72 + t];
  __syncthreads();
  int x = t >> 5, y = t & 31;
  float acc = bias[oc];
  const float* fb = ft + b*8192;
  for (int ic = 0; ic < 8; ++ic) {
    const float* fc = fb + ic*1024;
    const float* wr = Ws + ic*9;
#pragma unroll
    for (int dx = -1; dx <= 1; ++dx) {
      int xx = x + dx;
      bool okx = ((unsigned)xx < 32u);
#pragma unroll
      for (int dy = -1; dy <= 1; ++dy) {
        int yy = y + dy;
        float v = (okx && ((unsigned)yy < 32u)) ? fc[xx*32 + yy] : 0.f;
        acc = fmaf(v, wr[(dx+1)*3 + (dy+1)], acc);
      }
    }
  }
  h1[(b*32 + oc)*1024 + t] = fmaxf(acc, 0.f);
}

// ---------------- conv2 + fused quadrature reduce into WS[b,c] ----------------
__global__ __launch_bounds__(512) void k_conv2(const float* __restrict__ h1,
                        const float* __restrict__ W,
                        const float* __restrict__ bias,
                        const float* __restrict__ wq,
                        float* __restrict__ h2, float* __restrict__ WS) {
  int blk = blockIdx.x;            // 256 = b(8) * q(32);  q = ocquad(16) * xhalf(2)
  int b = blk >> 5, q = blk & 31;
  int oc0 = (q >> 1) * 4, xh = q & 1;
  __shared__ float Ws[4*288];
  int t = threadIdx.x;             // 512
  for (int idx = t; idx < 4*288; idx += 512) Ws[idx] = W[oc0*288 + idx];
  __syncthreads();
  int x = xh*16 + (t >> 5), y = t & 31;
  float a0 = bias[oc0+0], a1 = bias[oc0+1], a2 = bias[oc0+2], a3 = bias[oc0+3];
  const float* hb = h1 + b*32*1024;
  for (int ic = 0; ic < 32; ++ic) {
    const float* hc = hb + ic*1024;
    const float* w0 = Ws + 0*288 + ic*9;
    const float* w1 = Ws + 1*288 + ic*9;
    const float* w2 = Ws + 2*288 + ic*9;
    const float* w3 = Ws + 3*288 + ic*9;
#pragma unroll
    for (int dx = -1; dx <= 1; ++dx) {
      int xx = x + dx;
      bool okx = ((unsigned)xx < 32u);
#pragma unroll
      for (int dy = -1; dy <= 1; ++dy) {
        int yy = y + dy;
        float v = (okx && ((unsigned)yy < 32u)) ? hc[xx*32 + yy] : 0.f;
        int k = (dx+1)*3 + (dy+1);
        a0 = fmaf(v, w0[k], a0);
        a1 = fmaf(v, w1[k], a1);
        a2 = fmaf(v, w2[k], a2);
        a3 = fmaf(v, w3[k], a3);
      }
    }
  }
  float r0 = fmaxf(a0, 0.f), r1 = fmaxf(a1, 0.f);
  float r2 = fmaxf(a2, 0.f), r3 = fmaxf(a3, 0.f);
  int pp = x*32 + y;
  h2[(b*64 + oc0+0)*1024 + pp] = r0;
  h2[(b*64 + oc0+1)*1024 + pp] = r1;
  h2[(b*64 + oc0+2)*1024 + pp] = r2;
  h2[(b*64 + oc0+3)*1024 + pp] = r3;
  // fused: WS[b,c] += sum wq[y]*h2  (wave reduce -> 4 atomics/wave)
  float wqv = wq[y];
  float s0 = r0*wqv, s1 = r1*wqv, s2 = r2*wqv, s3 = r3*wqv;
#pragma unroll
  for (int m = 1; m < 64; m <<= 1) {
    s0 += __shfl_xor(s0, m, 64);
    s1 += __shfl_xor(s1, m, 64);
    s2 += __shfl_xor(s2, m, 64);
    s3 += __shfl_xor(s3, m, 64);
  }
  if ((t & 63) == 0) {
    atomicAdd(&WS[b*64 + oc0+0], s0);
    atomicAdd(&WS[b*64 + oc0+1], s1);
    atomicAdd(&WS[b*64 + oc0+2], s2);
    atomicAdd(&WS[b*64 + oc0+3], s3);
  }
}

// ---------------- head (MFMA): grid 512 = b(8)*x(32)*h(2), h = g-half ----------------
// GEMM1: C1[(g,d), y] = V[(g,d),c] . h2[c,y]; h3 = relu(C1+K[d]) -> f16 LDS
// GEMM2: out[e, (y,g)] = W2[e,d] . h3[d,(y,g)]
__global__ __launch_bounds__(512, 4) void k_head(
    const float* __restrict__ h2, const float* __restrict__ WS,
    const float* __restrict__ sgs,
    const float* __restrict__ Wc31, const float* __restrict__ bc31,
    const float* __restrict__ bc32,
    const half8* __restrict__ VswH, const half8* __restrict__ VswL,
    const half8* __restrict__ W2swH, const half8* __restrict__ W2swL,
    float* __restrict__ out, float* __restrict__ blockmax) {
  __shared__ __align__(16) _Float16 h3H[512*72];   // [rowc=y*16+gl][d sw], 72 KiB
  __shared__ float Ks[64];
  __shared__ float vbuf2[128];
  int blk = blockIdx.x;            // 512
  int b = blk >> 6, x = (blk >> 1) & 31, h = blk & 1;
  int t = threadIdx.x;             // 512 = 8 waves
  int lane = t & 63, w = t >> 6;
  int n16 = lane & 15, quad = lane >> 4;

  if (t < 64) {
    float acc = bc31[t];
    const float* wr = Wc31 + t*128 + 64;
    const float* wsb = WS + b*64;
    for (int c = 0; c < 64; ++c)
      acc = fmaf(wr[c], sgs[c]*wsb[c], acc);
    Ks[t] = acc;
  }

  // GEMM1 B-frags (h2) loaded directly from global, split f16
  half8 bh00, bh01, bh10, bh11, bl00, bl01, bl10, bl11;
  {
    const float* h2b = h2 + (size_t)b*64*1024 + x*32;
#pragma unroll
    for (int j = 0; j < 8; ++j) {
      int c0 = quad*8 + j;         // ks=0
      int c1 = 32 + c0;            // ks=1
      float f00 = h2b[c0*1024 + n16];
      float f01 = h2b[c1*1024 + n16];
      float f10 = h2b[c0*1024 + 16 + n16];
      float f11 = h2b[c1*1024 + 16 + n16];
      _Float16 g00 = (_Float16)f00, g01 = (_Float16)f01;
      _Float16 g10 = (_Float16)f10, g11 = (_Float16)f11;
      bh00[j] = g00;  bl00[j] = (_Float16)(f00 - (float)g00);
      bh01[j] = g01;  bl01[j] = (_Float16)(f01 - (float)g01);
      bh10[j] = g10;  bl10[j] = (_Float16)(f10 - (float)g10);
      bh11[j] = g11;  bl11[j] = (_Float16)(f11 - (float)g11);
    }
  }
  // GEMM2 A-frags (W2), resident
  int mt2 = w & 1;
  half8 a2h0 = W2swH[(mt2*2 + 0)*64 + lane];
  half8 a2h1 = W2swH[(mt2*2 + 1)*64 + lane];
  half8 a2l0 = W2swL[(mt2*2 + 0)*64 + lane];
  half8 a2l1 = W2swL[(mt2*2 + 1)*64 + lane];
  float bias_e[4];
#pragma unroll
  for (int r = 0; r < 4; ++r) bias_e[r] = bc32[mt2*16 + quad*4 + r];
  __syncthreads();                 // Ks ready

  // ---- phase A: GEMM1, wave owns mt = h*64 + w*8 + i ----
  for (int i = 0; i < 8; ++i) {
    int mt = h*64 + w*8 + i;
    half8 ah0 = VswH[(mt*2 + 0)*64 + lane];
    half8 ah1 = VswH[(mt*2 + 1)*64 + lane];
    half8 al0 = VswL[(mt*2 + 0)*64 + lane];
    half8 al1 = VswL[(mt*2 + 1)*64 + lane];
    floatx4 acc0 = {0.f, 0.f, 0.f, 0.f};
    floatx4 acc1 = {0.f, 0.f, 0.f, 0.f};
    acc0 = MFMA16(ah0, bh00, acc0);  acc1 = MFMA16(ah0, bh10, acc1);
    acc0 = MFMA16(ah0, bl00, acc0);  acc1 = MFMA16(ah0, bl10, acc1);
    acc0 = MFMA16(al0, bh00, acc0);  acc1 = MFMA16(al0, bh10, acc1);
    acc0 = MFMA16(ah1, bh01, acc0);  acc1 = MFMA16(ah1, bh11, acc1);
    acc0 = MFMA16(ah1, bl01, acc0);  acc1 = MFMA16(ah1, bl11, acc1);
    acc0 = MFMA16(al1, bh01, acc0);  acc1 = MFMA16(al1, bh11, acc1);
    int g = mt >> 2, gl = g & 15;
    int dbase = (mt & 3)*16 + quad*4;
    float4 kv = *(const float4*)&Ks[dbase];
#pragma unroll
    for (int nt = 0; nt < 2; ++nt) {
      floatx4 a = nt ? acc1 : acc0;
      int y = nt*16 + n16;
      int rowc = y*16 + gl;
      int dsw = (dbase + y*8) & 63;
      half4v hv;
      hv[0] = (_Float16)fmaxf(a[0] + kv.x, 0.f);
      hv[1] = (_Float16)fmaxf(a[1] + kv.y, 0.f);
      hv[2] = (_Float16)fmaxf(a[2] + kv.z, 0.f);
      hv[3] = (_Float16)fmaxf(a[3] + kv.w, 0.f);
      *(half4v*)&h3H[rowc*72 + dsw] = hv;
    }
  }
  __syncthreads();
  // ---- phase B: GEMM2, wave owns nt2 = (w>>1)*8 + i (= y), e-tile mt2 ----
  float vmax[4] = {-3.4e38f, -3.4e38f, -3.4e38f, -3.4e38f};
  for (int i = 0; i < 8; ++i) {
    int nt2 = (w >> 1)*8 + i;
    int rowc = nt2*16 + n16;       // gl = n16
    int dsw0 = (quad*8 + nt2*8) & 63;
    int dsw1 = (32 + quad*8 + nt2*8) & 63;
    half8 b2h0 = *(const half8*)&h3H[rowc*72 + dsw0];
    half8 b2h1 = *(const half8*)&h3H[rowc*72 + dsw1];
    floatx4 acc = {0.f, 0.f, 0.f, 0.f};
    acc = MFMA16(a2h0, b2h0, acc);
    acc = MFMA16(a2l0, b2h0, acc);
    acc = MFMA16(a2h1, b2h1, acc);
    acc = MFMA16(a2l1, b2h1, acc);
    int y = nt2, g = h*16 + n16;
    size_t base = (((size_t)(b*32 + mt2*16 + quad*4))*1024 + (size_t)(x*32 + y))*32 + g;
#pragma unroll
    for (int r = 0; r < 4; ++r) {
      float v = acc[r] + bias_e[r];
      out[base + (size_t)r*32768] = v;
      vmax[r] = fmaxf(vmax[r], v);
    }
  }
  // block max over e
#pragma unroll
  for (int m = 1; m < 16; m <<= 1) {
#pragma unroll
    for (int r = 0; r < 4; ++r)
      vmax[r] = fmaxf(vmax[r], __shfl_xor(vmax[r], m, 64));
  }
  if (n16 == 0) {
#pragma unroll
    for (int r = 0; r < 4; ++r) vbuf2[w*16 + quad*4 + r] = vmax[r];
  }
  __syncthreads();
  if (t < 32) {
    int e = t, m2 = e >> 4, el = e & 15;
    float mm = fmaxf(fmaxf(vbuf2[(m2+0)*16 + el], vbuf2[(m2+2)*16 + el]),
                     fmaxf(vbuf2[(m2+4)*16 + el], vbuf2[(m2+6)*16 + el]));
    blockmax[blk*32 + e] = mm;
  }
}

// ---------------- finalize: ft_g[b,e] = max over 64 sub-blocks (x,h) ----------------
__global__ void k_final(const float* __restrict__ blockmax, float* __restrict__ ftg) {
  int t = threadIdx.x;             // 256 = b(8)*e(32)
  int b = t >> 5, e = t & 31;
  float m = -3.4e38f;
  for (int s = 0; s < 64; ++s) m = fmaxf(m, blockmax[(b*64 + s)*32 + e]);
  ftg[b*32 + e] = m;
}

extern "C" void kernel_launch(void* const* d_in, const int* in_sizes, int n_in,
                              void* d_out, int out_size, void* d_ws, size_t ws_size,
                              hipStream_t stream) {
  const float* inputs = (const float*)d_in[0];
  const float* scale  = (const float*)d_in[1];
  const float* sigma  = (const float*)d_in[2];
  const float* A      = (const float*)d_in[3];
  const float* icmp   = (const float*)d_in[4];
  // d_in[5]=res_pt(32), d_in[6]=res_r(8) — compile-time constants here
  const float* W1   = (const float*)d_in[7];
  const float* b1   = (const float*)d_in[8];
  const float* W2   = (const float*)d_in[9];
  const float* b2   = (const float*)d_in[10];
  const float* Wg   = (const float*)d_in[11];
  const float* Wc31 = (const float*)d_in[12];
  const float* bc31 = (const float*)d_in[13];
  const float* Wc32 = (const float*)d_in[14];
  const float* bc32 = (const float*)d_in[15];

  float* ws    = (float*)d_ws;
  float* ft    = ws;               // 65536
  float* h1    = ws + 65536;       // 262144
  float* h2    = ws + 327680;      // 524288
  float* WS    = ws + 851968;      // 512
  float* bmax  = ws + 852480;      // 16384
  float* wq    = ws + 868864;      // 32
  float* sgs   = ws + 868896;      // 64
  _Float16* VswH  = (_Float16*)(ws + 868960);   // 131072 f16
  _Float16* VswL  = (_Float16*)(ws + 934496);   // 131072 f16
  _Float16* W2swH = (_Float16*)(ws + 1000032);  // 2048 f16
  _Float16* W2swL = (_Float16*)(ws + 1001056);  // 2048 f16
  float* out   = (float*)d_out;    // 8388608
  float* ftg   = out + 8388608;    // 256

  k_prep<<<512, 256, 0, stream>>>(Wg, Wc31, Wc32, VswH, VswL, W2swH, W2swL,
                                  ft, WS, wq, sgs);
  k_scatter<<<1024, 256, 0, stream>>>(inputs, scale, sigma, A, icmp, ft);
  k_conv1<<<256, 1024, 0, stream>>>(ft, W1, b1, h1);
  k_conv2<<<256, 512, 0, stream>>>(h1, W2, b2, wq, h2, WS);
  k_head<<<512, 512, 0, stream>>>(h2, WS, sgs, Wc31, bc31, bc32,
                                  (const half8*)VswH, (const half8*)VswL,
                                  (const half8*)W2swH, (const half8*)W2swL,
                                  out, bmax);
  k_final<<<1, 256, 0, stream>>>(bmax, ftg);
}